// Round 2
// baseline (801.841 us; speedup 1.0000x reference)
//
#include <hip/hip_runtime.h>
#include <cstdint>
#include <cstddef>

#define DMODEL 1024
#define DH 2048
#define BATCH 2
#define SEQ 4096
#define CHUNK 64
#define NCHUNK (SEQ/CHUNK)   // 64

typedef unsigned short u16;
typedef __attribute__((ext_vector_type(8))) short bf16x8;
typedef __attribute__((ext_vector_type(4))) float f32x4;

__device__ __forceinline__ u16 f2bf(float f) {
    union { float f; unsigned u; } v; v.f = f;
    unsigned r = v.u + 0x7FFFu + ((v.u >> 16) & 1u);
    return (u16)(r >> 16);
}
__device__ __forceinline__ float bf2f(u16 h) {
    union { unsigned u; float f; } v; v.u = ((unsigned)h) << 16; return v.f;
}

// ---------------- f32 -> bf16 conversion, 4 elems/thread ----------------
__global__ void cvt_bf16(const float* __restrict__ src, u16* __restrict__ dst, int n4) {
    int i = blockIdx.x * blockDim.x + threadIdx.x;
    if (i >= n4) return;
    const float4 v = reinterpret_cast<const float4*>(src)[i];
    ushort4 o;
    o.x = f2bf(v.x); o.y = f2bf(v.y); o.z = f2bf(v.z); o.w = f2bf(v.w);
    reinterpret_cast<ushort4*>(dst)[i] = o;
}

// ---------------- GEMM: C[M,N] = A[M,K] @ B[N,K]^T  (bf16 in, f32 acc) ----------------
// EP 0: C   = acc + bias                    (f32 out)
// EP 1: C  += acc + bias; Cb = bf16(C)      (read-modify-write + bf16 dup)
// EP 2: Cb  = bf16(aux * silu(acc))         (bf16 out only)
// EP 3: C   = aux + acc                     (f32 out, final)
// EP 4: Cb  = bf16(acc + bias)              (bf16 out only)
__device__ __forceinline__ void gload_lds16(const void* g, void* l) {
    __builtin_amdgcn_global_load_lds(
        (const __attribute__((address_space(1))) void*)g,
        (__attribute__((address_space(3))) void*)l,
        16, 0, 0);
}

template<int EP>
__global__ __launch_bounds__(256) void gemm_bt(
    const u16* __restrict__ A, const u16* __restrict__ Bm,
    float* __restrict__ C, u16* __restrict__ Cb,
    const float* __restrict__ bias, const float* __restrict__ aux,
    int M, int N, int K)
{
    constexpr int BM = 128, BN = 128, BK = 32;
    __shared__ u16 As[BM*BK];   // 8 KB, linear row-major [128][32]
    __shared__ u16 Bs[BN*BK];   // 8 KB
    const int tid = threadIdx.x;
    const int m0 = blockIdx.y * BM;
    const int n0 = blockIdx.x * BN;
    const int wave = tid >> 6, lane = tid & 63;
    const int wr = (wave >> 1) * 64;       // 2x2 wave grid, 64x64 each
    const int wc = (wave & 1) * 64;
    const int fr = lane & 15, fq = lane >> 4;

    f32x4 acc[4][4];
    #pragma unroll
    for (int m = 0; m < 4; m++)
        #pragma unroll
        for (int n = 0; n < 4; n++) acc[m][n] = f32x4{0.f, 0.f, 0.f, 0.f};

    for (int k0 = 0; k0 < K; k0 += BK) {
        #pragma unroll
        for (int i = 0; i < 2; ++i) {   // 256 thr * 16B * 2 = 8KB per matrix
            const int e = (i*256 + tid) * 8;         // element offset in tile
            const int r = e >> 5, c = e & 31;        // row / col within tile
            gload_lds16(A  + (size_t)(m0 + r)*K + (k0 + c), (char*)As + (size_t)e*2);
            gload_lds16(Bm + (size_t)(n0 + r)*K + (k0 + c), (char*)Bs + (size_t)e*2);
        }
        __syncthreads();

        bf16x8 af[4], bfr[4];
        #pragma unroll
        for (int m = 0; m < 4; m++)
            af[m] = *reinterpret_cast<const bf16x8*>(&As[(wr + m*16 + fr)*BK + fq*8]);
        #pragma unroll
        for (int n = 0; n < 4; n++)
            bfr[n] = *reinterpret_cast<const bf16x8*>(&Bs[(wc + n*16 + fr)*BK + fq*8]);
        #pragma unroll
        for (int m = 0; m < 4; m++)
            #pragma unroll
            for (int n = 0; n < 4; n++)
                acc[m][n] = __builtin_amdgcn_mfma_f32_16x16x32_bf16(af[m], bfr[n], acc[m][n], 0, 0, 0);
        __syncthreads();
    }

    #pragma unroll
    for (int m = 0; m < 4; m++) {
        #pragma unroll
        for (int n = 0; n < 4; n++) {
            const int col = n0 + wc + n*16 + fr;
            const float bv = bias ? bias[col] : 0.f;
            #pragma unroll
            for (int j = 0; j < 4; j++) {
                const int row = m0 + wr + m*16 + fq*4 + j;   // C row = (lane>>4)*4+reg
                const size_t idx = (size_t)row * N + col;
                float v = acc[m][n][j] + bv;
                if constexpr (EP == 0) {
                    C[idx] = v;
                } else if constexpr (EP == 1) {
                    float s = C[idx] + v;
                    C[idx] = s;
                    Cb[idx] = f2bf(s);
                } else if constexpr (EP == 2) {
                    float a = aux[idx];
                    float sl = v / (1.f + expf(-v));
                    Cb[idx] = f2bf(a * sl);
                } else if constexpr (EP == 3) {
                    C[idx] = aux[idx] + v;
                } else {   // EP 4
                    Cb[idx] = f2bf(v);
                }
            }
        }
    }
}

// ---------------- depthwise conv3 (pad 1) + silu, bf16 in/out, per batch ----------------
__global__ void conv_silu(const u16* __restrict__ x1, const float* __restrict__ cw,
                          const float* __restrict__ cb, u16* __restrict__ xab) {
    int i = blockIdx.x * blockDim.x + threadIdx.x;   // over SEQ*DMODEL
    int c = i & (DMODEL-1);
    int l = i >> 10;
    float xm = (l > 0)      ? bf2f(x1[i - DMODEL]) : 0.f;
    float x0 = bf2f(x1[i]);
    float xp = (l < SEQ-1)  ? bf2f(x1[i + DMODEL]) : 0.f;
    float v = cw[c*3+0]*xm + cw[c*3+1]*x0 + cw[c*3+2]*xp + cb[c];
    float s = v / (1.f + expf(-v));
    xab[i] = f2bf(s);
}

// ---------------- SSM chunked scan (per batch) ----------------
__device__ __forceinline__ float softplusf(float x) {
    return (x > 0.f) ? (x + log1pf(expf(-x))) : log1pf(expf(x));
}

__global__ void scan_chunks(const u16* __restrict__ pd, const u16* __restrict__ pB,
                            const float* __restrict__ Avec,
                            float* __restrict__ cA, float* __restrict__ cB) {
    const int c = blockIdx.x * blockDim.x + threadIdx.x;   // channel
    const int q = blockIdx.y;                              // chunk
    const float Ac = Avec[c];
    float hA = 1.f, hB = 0.f;
    size_t base = ((size_t)(q*CHUNK))*DH + c;
    for (int j = 0; j < CHUNK; ++j) {
        float d = softplusf(bf2f(pd[base]));
        float Abar = expf(d * Ac);
        float Bbar = d * bf2f(pB[base]);
        hA *= Abar;
        hB = Abar*hB + Bbar;
        base += DH;
    }
    size_t o = (size_t)q*DH + c;
    cA[o] = hA; cB[o] = hB;
}

__global__ void scan_prefix(const float* __restrict__ cA, const float* __restrict__ cB,
                            float* __restrict__ cH) {
    const int c = blockIdx.x * blockDim.x + threadIdx.x;   // 0..DH-1
    float h = 0.f;
    for (int q = 0; q < NCHUNK; ++q) {
        size_t o = (size_t)q*DH + c;
        cH[o] = h;                      // state BEFORE chunk q
        h = cA[o]*h + cB[o];
    }
}

__global__ void scan_apply(const u16* __restrict__ pd, const u16* __restrict__ pB,
                           const float* __restrict__ Avec, const float* __restrict__ cH,
                           u16* __restrict__ hstb) {
    const int c = blockIdx.x * blockDim.x + threadIdx.x;
    const int q = blockIdx.y;
    const float Ac = Avec[c];
    float h = cH[(size_t)q*DH + c];
    size_t base = ((size_t)(q*CHUNK))*DH + c;
    for (int j = 0; j < CHUNK; ++j) {
        float d = softplusf(bf2f(pd[base]));
        float Abar = expf(d * Ac);
        float Bbar = d * bf2f(pB[base]);
        h = Abar*h + Bbar;
        hstb[base] = f2bf(h);
        base += DH;
    }
}

// ---------------- host ----------------
extern "C" void kernel_launch(void* const* d_in, const int* in_sizes, int n_in,
                              void* d_out, int out_size, void* d_ws, size_t ws_size,
                              hipStream_t stream) {
    const float* x      = (const float*)d_in[0];
    const float* W1     = (const float*)d_in[1];
    const float* conv_w = (const float*)d_in[2];
    const float* conv_b = (const float*)d_in[3];
    const float* Avec   = (const float*)d_in[4];
    const float* Wb     = (const float*)d_in[5];
    const float* bb     = (const float*)d_in[6];
    const float* Wc     = (const float*)d_in[7];
    const float* bc     = (const float*)d_in[8];
    const float* Wd     = (const float*)d_in[9];
    const float* bd     = (const float*)d_in[10];
    const float* Wdelta = (const float*)d_in[11];
    const float* bdelta = (const float*)d_in[12];
    const float* W2     = (const float*)d_in[13];
    const float* Wlast  = (const float*)d_in[14];
    float* out = (float*)d_out;
    (void)in_sizes; (void)n_in; (void)out_size;

    // ---- workspace arena (aliased by lifetime), ~78 MB total ----
    char* ws = (char*)d_ws;
    size_t off = 0;
    auto alloc = [&](size_t bytes) -> void* {
        void* p = ws + off; off += (bytes + 255) & ~(size_t)255; return p;
    };
    u16*   wslot = (u16*)  alloc((size_t)DH*DMODEL*2);        // 4 MB, reused per weight
    float* cA    = (float*)alloc((size_t)NCHUNK*DH*4);        // 512 KB
    float* cBc   = (float*)alloc((size_t)NCHUNK*DH*4);
    float* cH    = (float*)alloc((size_t)NCHUNK*DH*4);
    char*  R0    = (char*) alloc((size_t)SEQ*DH*2);           // 16 MB: xb -> pd -> zb
    char*  R1    = (char*) alloc((size_t)SEQ*DH*2);           // 16 MB: x1b -> pB
    char*  R2    = (char*) alloc((size_t)SEQ*DMODEL*2);       //  8 MB: xab -> ossb
    char*  R3    = (char*) alloc((size_t)SEQ*DH*2);           // 16 MB: hstb
    char*  R4    = (char*) alloc((size_t)SEQ*DMODEL*4);       // 16 MB: oss (f32)
    if (ws_size < off) return;   // clean diagnostic fail (absmax == max|ref|) instead of fault

    u16*   xb   = (u16*)R0;  u16* pd   = (u16*)R0;  u16* zb = (u16*)R0;
    u16*   x1b  = (u16*)R1;  u16* pB   = (u16*)R1;
    u16*   xab  = (u16*)R2;  u16* ossb = (u16*)R2;
    u16*   hstb = (u16*)R3;
    float* oss  = (float*)R4;

    const dim3 blk(256);
    auto cvt = [&](const float* s, u16* d, size_t n) {
        int n4 = (int)(n / 4);
        cvt_bf16<<<dim3((n4 + 255)/256), blk, 0, stream>>>(s, d, n4);
    };

    const dim3 gD(DMODEL/128, SEQ/128);   // N=1024: 8x32
    const dim3 gH(DH/128,     SEQ/128);   // N=2048: 16x32

    for (int b = 0; b < BATCH; ++b) {
        const float* x_b  = x  + (size_t)b*SEQ*DMODEL;
        float*      out_b = out + (size_t)b*SEQ*DMODEL;

        cvt(x_b, xb, (size_t)SEQ*DMODEL);

        // x1 = x @ W1^T  (bf16 out)
        cvt(W1, wslot, (size_t)DMODEL*DMODEL);
        gemm_bt<4><<<gD, blk, 0, stream>>>(xb, wslot, nullptr, x1b, nullptr, nullptr, SEQ, DMODEL, DMODEL);
        // xa = silu(conv3(x1))
        conv_silu<<<dim3(SEQ*DMODEL/256), blk, 0, stream>>>(x1b, conv_w, conv_b, xab);
        // pre_delta (bf16), pre_B (bf16)
        cvt(Wdelta, wslot, (size_t)DH*DMODEL);
        gemm_bt<4><<<gH, blk, 0, stream>>>(xab, wslot, nullptr, pd, bdelta, nullptr, SEQ, DH, DMODEL);
        cvt(Wb, wslot, (size_t)DH*DMODEL);
        gemm_bt<4><<<gH, blk, 0, stream>>>(xab, wslot, nullptr, pB, bb, nullptr, SEQ, DH, DMODEL);
        // chunked scan -> h_st (bf16)
        scan_chunks<<<dim3(DH/256, NCHUNK), blk, 0, stream>>>(pd, pB, Avec, cA, cBc);
        scan_prefix<<<dim3(DH/256), blk, 0, stream>>>(cA, cBc, cH);
        scan_apply <<<dim3(DH/256, NCHUNK), blk, 0, stream>>>(pd, pB, Avec, cH, hstb);
        // oss = xa @ Wd^T + bd  (f32)
        cvt(Wd, wslot, (size_t)DMODEL*DMODEL);
        gemm_bt<0><<<gD, blk, 0, stream>>>(xab, wslot, oss, nullptr, bd, nullptr, SEQ, DMODEL, DMODEL);
        // oss += h_st @ Wc^T + bc;  ossb = bf16(oss)
        cvt(Wc, wslot, (size_t)DMODEL*DH);
        gemm_bt<1><<<gD, blk, 0, stream>>>(hstb, wslot, oss, ossb, bc, nullptr, SEQ, DMODEL, DH);
        // z = oss * silu(oss @ W2^T)   (bf16)
        cvt(W2, wslot, (size_t)DMODEL*DMODEL);
        gemm_bt<2><<<gD, blk, 0, stream>>>(ossb, wslot, nullptr, zb, nullptr, oss, SEQ, DMODEL, DMODEL);
        // out = oss + z @ Wlast^T
        cvt(Wlast, wslot, (size_t)DMODEL*DMODEL);
        gemm_bt<3><<<gD, blk, 0, stream>>>(zb, wslot, out_b, nullptr, nullptr, oss, SEQ, DMODEL, DMODEL);
    }
}

// Round 3
// 469.673 us; speedup vs baseline: 1.7072x; 1.7072x over previous
//
#include <hip/hip_runtime.h>
#include <cstdint>
#include <cstddef>

#define DMODEL 1024
#define DH 2048
#define BATCH 2
#define SEQ 4096
#define MROWS (BATCH*SEQ)    // 8192
#define CHUNK 64
#define NCHUNK (SEQ/CHUNK)   // 64

typedef unsigned short u16;
typedef __attribute__((ext_vector_type(8))) short bf16x8;
typedef __attribute__((ext_vector_type(4))) float f32x4;

__device__ __forceinline__ u16 f2bf(float f) {
    union { float f; unsigned u; } v; v.f = f;
    unsigned r = v.u + 0x7FFFu + ((v.u >> 16) & 1u);
    return (u16)(r >> 16);
}
__device__ __forceinline__ float bf2f(u16 h) {
    union { unsigned u; float f; } v; v.u = ((unsigned)h) << 16; return v.f;
}

// ---------------- f32 -> bf16, 4 elems/thread ----------------
__global__ void cvt_bf16(const float* __restrict__ src, u16* __restrict__ dst, int n4) {
    int i = blockIdx.x * blockDim.x + threadIdx.x;
    if (i >= n4) return;
    const float4 v = reinterpret_cast<const float4*>(src)[i];
    ushort4 o;
    o.x = f2bf(v.x); o.y = f2bf(v.y); o.z = f2bf(v.z); o.w = f2bf(v.w);
    reinterpret_cast<ushort4*>(dst)[i] = o;
}

// ---------------- GEMM: C[M,N] = A[M,K] @ B[N,K]^T  (bf16 in, f32 acc) ----------------
// m97 structure: 128x128 tile, BK=64, width-16 global_load_lds, XOR-swizzled LDS.
// Swizzle (both sides, rule 21): LDS[row][chunk] holds global [row][chunk ^ (row&7)],
// achieved by pre-swizzling the per-lane GLOBAL source address (LDS dest stays linear);
// reads XOR the chunk the same way. 16B chunks, row stride 128B.
// EP 0: Cb = bf16(acc + b1)                  (bf16 out)
// EP 1: C  = acc + b1 + b2; Cb = bf16(C)     (f32 + bf16 dual out; used by fused Wd/Wc)
// EP 2: Cb = bf16(aux * silu(acc))           (gate)
// EP 3: C  = aux + acc                       (final residual, f32 out)
__device__ __forceinline__ void gload_lds16(const void* g, void* l) {
    __builtin_amdgcn_global_load_lds(
        (const __attribute__((address_space(1))) void*)g,
        (__attribute__((address_space(3))) void*)l,
        16, 0, 0);
}

template<int EP, bool TWOK>
__global__ __launch_bounds__(256) void gemm_bt(
    const u16* __restrict__ A1, const u16* __restrict__ B1, int K1,
    const u16* __restrict__ A2, const u16* __restrict__ B2, int K2,
    float* __restrict__ C, u16* __restrict__ Cb,
    const float* __restrict__ bias, const float* __restrict__ bias2,
    const float* __restrict__ aux,
    int M, int N)
{
    __shared__ u16 As[128*64];   // 16 KB
    __shared__ u16 Bs[128*64];   // 16 KB
    const int tid = threadIdx.x;
    const int m0 = blockIdx.y * 128;
    const int n0 = blockIdx.x * 128;
    const int wave = tid >> 6, lane = tid & 63;
    const int wr = (wave >> 1) * 64;     // 2x2 wave grid, 64x64 per wave
    const int wc = (wave & 1) * 64;
    const int fr = lane & 15, fq = lane >> 4;

    f32x4 acc[4][4];
    #pragma unroll
    for (int m = 0; m < 4; m++)
        #pragma unroll
        for (int n = 0; n < 4; n++) acc[m][n] = f32x4{0.f, 0.f, 0.f, 0.f};

    const int nseg = TWOK ? 2 : 1;
    for (int seg = 0; seg < nseg; ++seg) {
        const u16* A = (TWOK && seg) ? A2 : A1;
        const u16* B = (TWOK && seg) ? B2 : B1;
        const int  K = (TWOK && seg) ? K2 : K1;
        for (int k0 = 0; k0 < K; k0 += 64) {
            #pragma unroll
            for (int i = 0; i < 4; ++i) {         // 1024 granules of 16B per matrix
                const int g = i*256 + tid;
                const int r = g >> 3;             // tile row
                const int ch = (g & 7) ^ (r & 7); // pre-swizzled source chunk
                gload_lds16(A + (size_t)(m0 + r)*K + (k0 + ch*8), (char*)As + (size_t)g*16);
                gload_lds16(B + (size_t)(n0 + r)*K + (k0 + ch*8), (char*)Bs + (size_t)g*16);
            }
            __syncthreads();
            #pragma unroll
            for (int kk = 0; kk < 2; ++kk) {
                bf16x8 af[4], bfr[4];
                #pragma unroll
                for (int m = 0; m < 4; m++) {
                    const int r = wr + m*16 + fr;
                    af[m] = *reinterpret_cast<const bf16x8*>(
                        (const char*)As + r*128 + (((kk*4 + fq) ^ (r & 7)) * 16));
                }
                #pragma unroll
                for (int n = 0; n < 4; n++) {
                    const int r = wc + n*16 + fr;
                    bfr[n] = *reinterpret_cast<const bf16x8*>(
                        (const char*)Bs + r*128 + (((kk*4 + fq) ^ (r & 7)) * 16));
                }
                #pragma unroll
                for (int m = 0; m < 4; m++)
                    #pragma unroll
                    for (int n = 0; n < 4; n++)
                        acc[m][n] = __builtin_amdgcn_mfma_f32_16x16x32_bf16(af[m], bfr[n], acc[m][n], 0, 0, 0);
            }
            __syncthreads();
        }
    }

    #pragma unroll
    for (int m = 0; m < 4; m++) {
        #pragma unroll
        for (int n = 0; n < 4; n++) {
            const int col = n0 + wc + n*16 + fr;
            float bv = 0.f;
            if (bias)  bv += bias[col];
            if (bias2) bv += bias2[col];
            #pragma unroll
            for (int j = 0; j < 4; j++) {
                const int row = m0 + wr + m*16 + fq*4 + j;   // C row = (lane>>4)*4+reg
                const size_t idx = (size_t)row * N + col;
                float v = acc[m][n][j] + bv;
                if constexpr (EP == 0) {
                    Cb[idx] = f2bf(v);
                } else if constexpr (EP == 1) {
                    C[idx] = v;
                    Cb[idx] = f2bf(v);
                } else if constexpr (EP == 2) {
                    float a = aux[idx];
                    float sl = v / (1.f + expf(-v));
                    Cb[idx] = f2bf(a * sl);
                } else {
                    C[idx] = aux[idx] + v;
                }
            }
        }
    }
}

// ---------------- depthwise conv3 (pad 1, per seq of 4096) + silu, bf16x8 ----------------
__global__ void conv_silu8(const u16* __restrict__ x1, const float* __restrict__ cw,
                           const float* __restrict__ cb, u16* __restrict__ xab) {
    int t = blockIdx.x * blockDim.x + threadIdx.x;   // over Mp*DMODEL/8
    int c8  = t & (DMODEL/8 - 1);
    int row = t >> 7;
    int l = row & (SEQ - 1);
    const int c0 = c8 * 8;
    const size_t i0 = (size_t)row * DMODEL + c0;
    bf16x8 v0 = *reinterpret_cast<const bf16x8*>(x1 + i0);
    bf16x8 vm = {}; if (l > 0)       vm = *reinterpret_cast<const bf16x8*>(x1 + i0 - DMODEL);
    bf16x8 vp = {}; if (l < SEQ - 1) vp = *reinterpret_cast<const bf16x8*>(x1 + i0 + DMODEL);
    if (l == 0)       vm = bf16x8{};
    if (l == SEQ - 1) vp = bf16x8{};
    bf16x8 o;
    #pragma unroll
    for (int j = 0; j < 8; ++j) {
        const int c = c0 + j;
        float v = cw[c*3+0]*bf2f((u16)vm[j]) + cw[c*3+1]*bf2f((u16)v0[j])
                + cw[c*3+2]*bf2f((u16)vp[j]) + cb[c];
        float s = v / (1.f + expf(-v));
        o[j] = (short)f2bf(s);
    }
    *reinterpret_cast<bf16x8*>(xab + i0) = o;
}

// ---------------- SSM chunked scan (batch in grid.z) ----------------
__device__ __forceinline__ float softplusf(float x) {
    return (x > 0.f) ? (x + log1pf(expf(-x))) : log1pf(expf(x));
}

__global__ void scan_chunks(const u16* __restrict__ pd, const u16* __restrict__ pB,
                            const float* __restrict__ Avec,
                            float* __restrict__ cA, float* __restrict__ cB) {
    const int c = blockIdx.x * blockDim.x + threadIdx.x;
    const int q = blockIdx.y;
    const int b = blockIdx.z;
    const float Ac = Avec[c];
    float hA = 1.f, hB = 0.f;
    size_t base = ((size_t)b*SEQ + q*CHUNK)*DH + c;
    for (int j = 0; j < CHUNK; ++j) {
        float d = softplusf(bf2f(pd[base]));
        float Abar = expf(d * Ac);
        hA *= Abar;
        hB = Abar*hB + d * bf2f(pB[base]);
        base += DH;
    }
    size_t o = ((size_t)b*NCHUNK + q)*DH + c;
    cA[o] = hA; cB[o] = hB;
}

__global__ void scan_prefix(const float* __restrict__ cA, const float* __restrict__ cB,
                            float* __restrict__ cH) {
    const int t = blockIdx.x * blockDim.x + threadIdx.x;   // nb*DH
    const int b = t >> 11;          // /DH
    const int c = t & (DH - 1);
    float h = 0.f;
    size_t o = ((size_t)b*NCHUNK)*DH + c;
    float a = cA[o], bb = cB[o];
    for (int q = 0; q < NCHUNK; ++q) {
        const size_t on = o + DH;
        float a2 = 0.f, b2 = 0.f;
        if (q + 1 < NCHUNK) { a2 = cA[on]; b2 = cB[on]; }   // prefetch next
        cH[o] = h;                   // state BEFORE chunk q
        h = a*h + bb;
        a = a2; bb = b2; o = on;
    }
}

__global__ void scan_apply(const u16* __restrict__ pd, const u16* __restrict__ pB,
                           const float* __restrict__ Avec, const float* __restrict__ cH,
                           u16* __restrict__ hstb) {
    const int c = blockIdx.x * blockDim.x + threadIdx.x;
    const int q = blockIdx.y;
    const int b = blockIdx.z;
    const float Ac = Avec[c];
    float h = cH[((size_t)b*NCHUNK + q)*DH + c];
    size_t base = ((size_t)b*SEQ + q*CHUNK)*DH + c;
    for (int j = 0; j < CHUNK; ++j) {
        float d = softplusf(bf2f(pd[base]));
        float Abar = expf(d * Ac);
        h = Abar*h + d * bf2f(pB[base]);
        hstb[base] = f2bf(h);
        base += DH;
    }
}

// ---------------- host ----------------
extern "C" void kernel_launch(void* const* d_in, const int* in_sizes, int n_in,
                              void* d_out, int out_size, void* d_ws, size_t ws_size,
                              hipStream_t stream) {
    const float* x      = (const float*)d_in[0];
    const float* W1     = (const float*)d_in[1];
    const float* conv_w = (const float*)d_in[2];
    const float* conv_b = (const float*)d_in[3];
    const float* Avec   = (const float*)d_in[4];
    const float* Wb     = (const float*)d_in[5];
    const float* bb     = (const float*)d_in[6];
    const float* Wc     = (const float*)d_in[7];
    const float* bc     = (const float*)d_in[8];
    const float* Wd     = (const float*)d_in[9];
    const float* bd     = (const float*)d_in[10];
    const float* Wdelta = (const float*)d_in[11];
    const float* bdelta = (const float*)d_in[12];
    const float* W2     = (const float*)d_in[13];
    const float* Wlast  = (const float*)d_in[14];
    float* out = (float*)d_out;
    (void)in_sizes; (void)n_in; (void)out_size;

    // ---- layout (aliased by lifetime); prefer full-batch (1 pass), else 2 passes ----
    struct Ptrs {
        u16 *sA, *sB;             // weight slots (4 MB each)
        float *cA, *cB, *cH;
        u16 *xb, *x1b, *xab, *pd, *pB, *ossb, *hstb, *zb;
        float *oss;
        size_t total;
    };
    auto layout = [&](int passes) -> Ptrs {
        Ptrs P{};
        const size_t Mp = MROWS / passes;
        const int nb = BATCH / passes;
        size_t off = 0;
        auto al = [&](size_t bytes) -> char* {
            char* p = (char*)d_ws + off; off += (bytes + 255) & ~(size_t)255; return p;
        };
        P.sA  = (u16*)al((size_t)DH*DMODEL*2);        // 4 MB
        P.sB  = (u16*)al((size_t)DMODEL*DH*2);        // 4 MB
        P.cA  = (float*)al((size_t)nb*NCHUNK*DH*4);
        P.cB  = (float*)al((size_t)nb*NCHUNK*DH*4);
        P.cH  = (float*)al((size_t)nb*NCHUNK*DH*4);
        char* RA = al(Mp*DMODEL*2*2);                 // xb | x1b -> hstb
        char* RB = al(Mp*DMODEL*2);                   // xab -> zb
        char* RC = al(Mp*DH*2);                       // pd
        char* RD = al(Mp*DH*2);                       // pB -> oss (f32, same bytes)
        char* RE = al(Mp*DMODEL*2);                   // ossb
        P.xb  = (u16*)RA; P.x1b = (u16*)(RA + Mp*DMODEL*2); P.hstb = (u16*)RA;
        P.xab = (u16*)RB; P.zb = (u16*)RB;
        P.pd  = (u16*)RC;
        P.pB  = (u16*)RD; P.oss = (float*)RD;
        P.ossb= (u16*)RE;
        P.total = off;
        return P;
    };

    int passes = (ws_size >= layout(1).total) ? 1 : 2;
    Ptrs P = layout(passes);
    if (ws_size < P.total) return;   // clean diagnostic fail instead of fault
    const int Mp = MROWS / passes;
    const int nb = BATCH / passes;

    const dim3 blk(256);
    auto cvt = [&](const float* s, u16* d, size_t n) {
        int n4 = (int)(n / 4);
        cvt_bf16<<<dim3((n4 + 255)/256), blk, 0, stream>>>(s, d, n4);
    };
    const dim3 gD(DMODEL/128, Mp/128);
    const dim3 gH(DH/128,     Mp/128);

    for (int p = 0; p < passes; ++p) {
        const float* x_p  = x  + (size_t)p*Mp*DMODEL;
        float*      out_p = out + (size_t)p*Mp*DMODEL;

        cvt(x_p, P.xb, (size_t)Mp*DMODEL);
        // x1 = x @ W1^T
        cvt(W1, P.sA, (size_t)DMODEL*DMODEL);
        gemm_bt<0,false><<<gD, blk, 0, stream>>>(P.xb, P.sA, DMODEL, nullptr, nullptr, 0,
                                                 nullptr, P.x1b, nullptr, nullptr, nullptr, Mp, DMODEL);
        // xa = silu(conv3(x1))
        conv_silu8<<<dim3(Mp*DMODEL/8/256), blk, 0, stream>>>(P.x1b, conv_w, conv_b, P.xab);
        // pre_delta, pre_B
        cvt(Wdelta, P.sA, (size_t)DH*DMODEL);
        gemm_bt<0,false><<<gH, blk, 0, stream>>>(P.xab, P.sA, DMODEL, nullptr, nullptr, 0,
                                                 nullptr, P.pd, bdelta, nullptr, nullptr, Mp, DH);
        cvt(Wb, P.sA, (size_t)DH*DMODEL);
        gemm_bt<0,false><<<gH, blk, 0, stream>>>(P.xab, P.sA, DMODEL, nullptr, nullptr, 0,
                                                 nullptr, P.pB, bb, nullptr, nullptr, Mp, DH);
        // chunked scan -> h_st (bf16)
        scan_chunks<<<dim3(DH/256, NCHUNK, nb), blk, 0, stream>>>(P.pd, P.pB, Avec, P.cA, P.cB);
        scan_prefix<<<dim3(nb*DH/256), blk, 0, stream>>>(P.cA, P.cB, P.cH);
        scan_apply <<<dim3(DH/256, NCHUNK, nb), blk, 0, stream>>>(P.pd, P.pB, Avec, P.cH, P.hstb);
        // oss = xa @ Wd^T + h_st @ Wc^T + (bd+bc)   (f32 + bf16 dual out, fused two-K GEMM)
        cvt(Wd, P.sA, (size_t)DMODEL*DMODEL);
        cvt(Wc, P.sB, (size_t)DMODEL*DH);
        gemm_bt<1,true><<<gD, blk, 0, stream>>>(P.xab, P.sA, DMODEL, P.hstb, P.sB, DH,
                                                P.oss, P.ossb, bd, bc, nullptr, Mp, DMODEL);
        // z = oss * silu(oss @ W2^T)
        cvt(W2, P.sA, (size_t)DMODEL*DMODEL);
        gemm_bt<2,false><<<gD, blk, 0, stream>>>(P.ossb, P.sA, DMODEL, nullptr, nullptr, 0,
                                                 nullptr, P.zb, nullptr, nullptr, P.oss, Mp, DMODEL);
        // out = oss + z @ Wlast^T
        cvt(Wlast, P.sA, (size_t)DMODEL*DMODEL);
        gemm_bt<3,false><<<gD, blk, 0, stream>>>(P.zb, P.sA, DMODEL, nullptr, nullptr, 0,
                                                 out_p, nullptr, nullptr, nullptr, P.oss, Mp, DMODEL);
    }
}

// Round 4
// 389.716 us; speedup vs baseline: 2.0575x; 1.2052x over previous
//
#include <hip/hip_runtime.h>
#include <cstdint>
#include <cstddef>

#define DMODEL 1024
#define DH 2048
#define BATCH 2
#define SEQ 4096
#define MROWS (BATCH*SEQ)    // 8192
#define CHUNK 64
#define NCHUNK (SEQ/CHUNK)   // 64

typedef unsigned short u16;
typedef __attribute__((ext_vector_type(8))) short bf16x8;
typedef __attribute__((ext_vector_type(4))) float f32x4;

__device__ __forceinline__ u16 f2bf(float f) {
    union { float f; unsigned u; } v; v.f = f;
    unsigned r = v.u + 0x7FFFu + ((v.u >> 16) & 1u);
    return (u16)(r >> 16);
}
__device__ __forceinline__ float bf2f(u16 h) {
    union { unsigned u; float f; } v; v.u = ((unsigned)h) << 16; return v.f;
}

// ---------------- f32 -> bf16, 4 elems/thread ----------------
__global__ void cvt_bf16(const float* __restrict__ src, u16* __restrict__ dst, int n4) {
    int i = blockIdx.x * blockDim.x + threadIdx.x;
    if (i >= n4) return;
    const float4 v = reinterpret_cast<const float4*>(src)[i];
    ushort4 o;
    o.x = f2bf(v.x); o.y = f2bf(v.y); o.z = f2bf(v.z); o.w = f2bf(v.w);
    reinterpret_cast<ushort4*>(dst)[i] = o;
}

// ---------------- GEMM: C[M,N] = A[M,K] @ B[N,K]^T  (bf16 in, f32 acc) ----------------
// 128x128 tile, BK=64, width-16 global_load_lds, XOR-swizzled LDS (both sides, rule 21),
// bijective XCD block swizzle (T1/m204; all grids have nwg%8==0).
// EP 0: Cb = bf16(acc + b1)
// EP 1: C  = acc + b1 + b2; Cb = bf16(C)     (fused Wd/Wc dual-out)
// EP 2: Cb = bf16(aux * silu(acc))           (gate)
// EP 3: C  = aux + acc                       (final residual, f32 out)
// EP 4: Cb = bf16(softplus(acc + b1))        (delta)
__device__ __forceinline__ void gload_lds16(const void* g, void* l) {
    __builtin_amdgcn_global_load_lds(
        (const __attribute__((address_space(1))) void*)g,
        (__attribute__((address_space(3))) void*)l,
        16, 0, 0);
}

__device__ __forceinline__ float softplusf(float x) {
    return (x > 0.f) ? (x + log1pf(expf(-x))) : log1pf(expf(x));
}

template<int EP, bool TWOK>
__global__ __launch_bounds__(256) void gemm_bt(
    const u16* __restrict__ A1, const u16* __restrict__ B1, int K1,
    const u16* __restrict__ A2, const u16* __restrict__ B2, int K2,
    float* __restrict__ C, u16* __restrict__ Cb,
    const float* __restrict__ bias, const float* __restrict__ bias2,
    const float* __restrict__ aux,
    int M, int N)
{
    __shared__ u16 As[128*64];   // 16 KB
    __shared__ u16 Bs[128*64];   // 16 KB
    const int tid = threadIdx.x;

    // XCD-aware bijective block swizzle (nwg % 8 == 0 for all our grids)
    const int nwg = gridDim.x * gridDim.y;
    int wg = blockIdx.y * gridDim.x + blockIdx.x;
    wg = (wg & 7) * (nwg >> 3) + (wg >> 3);
    const int m0 = (wg / gridDim.x) * 128;
    const int n0 = (wg % gridDim.x) * 128;

    const int wave = tid >> 6, lane = tid & 63;
    const int wr = (wave >> 1) * 64;     // 2x2 wave grid, 64x64 per wave
    const int wc = (wave & 1) * 64;
    const int fr = lane & 15, fq = lane >> 4;

    f32x4 acc[4][4];
    #pragma unroll
    for (int m = 0; m < 4; m++)
        #pragma unroll
        for (int n = 0; n < 4; n++) acc[m][n] = f32x4{0.f, 0.f, 0.f, 0.f};

    const int nseg = TWOK ? 2 : 1;
    for (int seg = 0; seg < nseg; ++seg) {
        const u16* A = (TWOK && seg) ? A2 : A1;
        const u16* B = (TWOK && seg) ? B2 : B1;
        const int  K = (TWOK && seg) ? K2 : K1;
        for (int k0 = 0; k0 < K; k0 += 64) {
            #pragma unroll
            for (int i = 0; i < 4; ++i) {         // 1024 granules of 16B per matrix
                const int g = i*256 + tid;
                const int r = g >> 3;             // tile row
                const int ch = (g & 7) ^ (r & 7); // pre-swizzled source chunk
                gload_lds16(A + (size_t)(m0 + r)*K + (k0 + ch*8), (char*)As + (size_t)g*16);
                gload_lds16(B + (size_t)(n0 + r)*K + (k0 + ch*8), (char*)Bs + (size_t)g*16);
            }
            __syncthreads();
            #pragma unroll
            for (int kk = 0; kk < 2; ++kk) {
                bf16x8 af[4], bfr[4];
                #pragma unroll
                for (int m = 0; m < 4; m++) {
                    const int r = wr + m*16 + fr;
                    af[m] = *reinterpret_cast<const bf16x8*>(
                        (const char*)As + r*128 + (((kk*4 + fq) ^ (r & 7)) * 16));
                }
                #pragma unroll
                for (int n = 0; n < 4; n++) {
                    const int r = wc + n*16 + fr;
                    bfr[n] = *reinterpret_cast<const bf16x8*>(
                        (const char*)Bs + r*128 + (((kk*4 + fq) ^ (r & 7)) * 16));
                }
                #pragma unroll
                for (int m = 0; m < 4; m++)
                    #pragma unroll
                    for (int n = 0; n < 4; n++)
                        acc[m][n] = __builtin_amdgcn_mfma_f32_16x16x32_bf16(af[m], bfr[n], acc[m][n], 0, 0, 0);
            }
            __syncthreads();
        }
    }

    #pragma unroll
    for (int m = 0; m < 4; m++) {
        #pragma unroll
        for (int n = 0; n < 4; n++) {
            const int col = n0 + wc + n*16 + fr;
            float bv = 0.f;
            if (bias)  bv += bias[col];
            if (bias2) bv += bias2[col];
            #pragma unroll
            for (int j = 0; j < 4; j++) {
                const int row = m0 + wr + m*16 + fq*4 + j;   // C row = (lane>>4)*4+reg
                const size_t idx = (size_t)row * N + col;
                float v = acc[m][n][j] + bv;
                if constexpr (EP == 0) {
                    Cb[idx] = f2bf(v);
                } else if constexpr (EP == 1) {
                    C[idx] = v;
                    Cb[idx] = f2bf(v);
                } else if constexpr (EP == 2) {
                    float a = aux[idx];
                    float sl = v / (1.f + expf(-v));
                    Cb[idx] = f2bf(a * sl);
                } else if constexpr (EP == 3) {
                    C[idx] = aux[idx] + v;
                } else {   // EP 4: delta = softplus(v)
                    Cb[idx] = f2bf(softplusf(v));
                }
            }
        }
    }
}

// ---------------- depthwise conv3 (pad 1, per seq of 4096) + silu, bf16x8 ----------------
__global__ void conv_silu8(const u16* __restrict__ x1, const float* __restrict__ cw,
                           const float* __restrict__ cb, u16* __restrict__ xab) {
    int t = blockIdx.x * blockDim.x + threadIdx.x;   // over Mp*DMODEL/8
    int c8  = t & (DMODEL/8 - 1);
    int row = t >> 7;
    int l = row & (SEQ - 1);
    const int c0 = c8 * 8;
    const size_t i0 = (size_t)row * DMODEL + c0;
    bf16x8 v0 = *reinterpret_cast<const bf16x8*>(x1 + i0);
    bf16x8 vm = {}; if (l > 0)       vm = *reinterpret_cast<const bf16x8*>(x1 + i0 - DMODEL);
    bf16x8 vp = {}; if (l < SEQ - 1) vp = *reinterpret_cast<const bf16x8*>(x1 + i0 + DMODEL);
    if (l == 0)       vm = bf16x8{};
    if (l == SEQ - 1) vp = bf16x8{};
    bf16x8 o;
    #pragma unroll
    for (int j = 0; j < 8; ++j) {
        const int c = c0 + j;
        float v = cw[c*3+0]*bf2f((u16)vm[j]) + cw[c*3+1]*bf2f((u16)v0[j])
                + cw[c*3+2]*bf2f((u16)vp[j]) + cb[c];
        float s = v / (1.f + expf(-v));
        o[j] = (short)f2bf(s);
    }
    *reinterpret_cast<bf16x8*>(xab + i0) = o;
}

// ---------------- SSM chunked scan (batch in grid.z) ----------------
// delta (bf16) and pBv = pre_B + bb (bf16) are precomputed by GEMM epilogues.
// Per element: Abar = expf(delta*Ac); h = Abar*h + delta*pBv. One transcendental.
__global__ void scan_chunks(const u16* __restrict__ delta, const u16* __restrict__ pBv,
                            const float* __restrict__ Avec,
                            float* __restrict__ cA, float* __restrict__ cB) {
    const int c = blockIdx.x * blockDim.x + threadIdx.x;
    const int q = blockIdx.y;
    const int b = blockIdx.z;
    const float Ac = Avec[c];
    float hA = 1.f, hB = 0.f;
    size_t base = ((size_t)b*SEQ + q*CHUNK)*DH + c;
    for (int j = 0; j < CHUNK; ++j) {
        float d = bf2f(delta[base]);
        float Abar = expf(d * Ac);
        hA *= Abar;
        hB = Abar*hB + d * bf2f(pBv[base]);
        base += DH;
    }
    size_t o = ((size_t)b*NCHUNK + q)*DH + c;
    cA[o] = hA; cB[o] = hB;
}

__global__ void scan_prefix(const float* __restrict__ cA, const float* __restrict__ cB,
                            float* __restrict__ cH) {
    const int t = blockIdx.x * blockDim.x + threadIdx.x;   // nb*DH
    const int b = t >> 11;          // /DH
    const int c = t & (DH - 1);
    float h = 0.f;
    size_t o = ((size_t)b*NCHUNK)*DH + c;
    float a = cA[o], bb = cB[o];
    for (int q = 0; q < NCHUNK; ++q) {
        const size_t on = o + DH;
        float a2 = 0.f, b2 = 0.f;
        if (q + 1 < NCHUNK) { a2 = cA[on]; b2 = cB[on]; }   // prefetch next
        cH[o] = h;                   // state BEFORE chunk q
        h = a*h + bb;
        a = a2; bb = b2; o = on;
    }
}

__global__ void scan_apply(const u16* __restrict__ delta, const u16* __restrict__ pBv,
                           const float* __restrict__ Avec, const float* __restrict__ cH,
                           u16* __restrict__ hstb) {
    const int c = blockIdx.x * blockDim.x + threadIdx.x;
    const int q = blockIdx.y;
    const int b = blockIdx.z;
    const float Ac = Avec[c];
    float h = cH[((size_t)b*NCHUNK + q)*DH + c];
    size_t base = ((size_t)b*SEQ + q*CHUNK)*DH + c;
    for (int j = 0; j < CHUNK; ++j) {
        float d = bf2f(delta[base]);
        float Abar = expf(d * Ac);
        h = Abar*h + d * bf2f(pBv[base]);
        hstb[base] = f2bf(h);
        base += DH;
    }
}

// ---------------- host ----------------
extern "C" void kernel_launch(void* const* d_in, const int* in_sizes, int n_in,
                              void* d_out, int out_size, void* d_ws, size_t ws_size,
                              hipStream_t stream) {
    const float* x      = (const float*)d_in[0];
    const float* W1     = (const float*)d_in[1];
    const float* conv_w = (const float*)d_in[2];
    const float* conv_b = (const float*)d_in[3];
    const float* Avec   = (const float*)d_in[4];
    const float* Wb     = (const float*)d_in[5];
    const float* bb     = (const float*)d_in[6];
    const float* Wc     = (const float*)d_in[7];
    const float* bc     = (const float*)d_in[8];
    const float* Wd     = (const float*)d_in[9];
    const float* bd     = (const float*)d_in[10];
    const float* Wdelta = (const float*)d_in[11];
    const float* bdelta = (const float*)d_in[12];
    const float* W2     = (const float*)d_in[13];
    const float* Wlast  = (const float*)d_in[14];
    float* out = (float*)d_out;
    (void)in_sizes; (void)n_in; (void)out_size;

    // ---- layout (aliased by lifetime); prefer full-batch (1 pass), else 2 passes ----
    struct Ptrs {
        u16 *sA, *sB;
        float *cA, *cB, *cH;
        u16 *xb, *x1b, *xab, *delta, *pBv, *ossb, *hstb, *zb;
        float *oss;
        size_t total;
    };
    auto layout = [&](int passes) -> Ptrs {
        Ptrs P{};
        const size_t Mp = MROWS / passes;
        const int nb = BATCH / passes;
        size_t off = 0;
        auto al = [&](size_t bytes) -> char* {
            char* p = (char*)d_ws + off; off += (bytes + 255) & ~(size_t)255; return p;
        };
        P.sA  = (u16*)al((size_t)DH*DMODEL*2);        // 4 MB
        P.sB  = (u16*)al((size_t)DMODEL*DH*2);        // 4 MB
        P.cA  = (float*)al((size_t)nb*NCHUNK*DH*4);
        P.cB  = (float*)al((size_t)nb*NCHUNK*DH*4);
        P.cH  = (float*)al((size_t)nb*NCHUNK*DH*4);
        char* RA = al(Mp*DMODEL*2);                   // xb -> ossb
        char* RB = al(Mp*DMODEL*2);                   // x1b -> zb
        char* RC = al(Mp*DMODEL*2);                   // xab
        char* RD = al(Mp*DH*2);                       // delta -> oss (f32 Mp*DMODEL*4, same bytes)
        char* RE = al(Mp*DH*2);                       // pBv
        char* RF = al(Mp*DH*2);                       // hstb
        P.xb    = (u16*)RA; P.ossb = (u16*)RA;
        P.x1b   = (u16*)RB; P.zb   = (u16*)RB;
        P.xab   = (u16*)RC;
        P.delta = (u16*)RD; P.oss  = (float*)RD;
        P.pBv   = (u16*)RE;
        P.hstb  = (u16*)RF;
        P.total = off;
        return P;
    };

    int passes = (ws_size >= layout(1).total) ? 1 : 2;
    Ptrs P = layout(passes);
    if (ws_size < P.total) return;   // clean diagnostic fail instead of fault
    const int Mp = MROWS / passes;
    const int nb = BATCH / passes;

    const dim3 blk(256);
    auto cvt = [&](const float* s, u16* d, size_t n) {
        int n4 = (int)(n / 4);
        cvt_bf16<<<dim3((n4 + 255)/256), blk, 0, stream>>>(s, d, n4);
    };
    const dim3 gD(DMODEL/128, Mp/128);   // 512 blocks (1-pass)
    const dim3 gH(DH/128,     Mp/128);   // 1024 blocks

    for (int p = 0; p < passes; ++p) {
        const float* x_p  = x  + (size_t)p*Mp*DMODEL;
        float*      out_p = out + (size_t)p*Mp*DMODEL;

        cvt(x_p, P.xb, (size_t)Mp*DMODEL);
        // x1 = x @ W1^T
        cvt(W1, P.sA, (size_t)DMODEL*DMODEL);
        gemm_bt<0,false><<<gD, blk, 0, stream>>>(P.xb, P.sA, DMODEL, nullptr, nullptr, 0,
                                                 nullptr, P.x1b, nullptr, nullptr, nullptr, Mp, DMODEL);
        // xa = silu(conv3(x1))
        conv_silu8<<<dim3(Mp*DMODEL/8/256), blk, 0, stream>>>(P.x1b, conv_w, conv_b, P.xab);
        // delta = softplus(xa @ Wdelta^T + bdelta)   (bf16, EP4)
        cvt(Wdelta, P.sA, (size_t)DH*DMODEL);
        gemm_bt<4,false><<<gH, blk, 0, stream>>>(P.xab, P.sA, DMODEL, nullptr, nullptr, 0,
                                                 nullptr, P.delta, bdelta, nullptr, nullptr, Mp, DH);
        // pBv = xa @ Wb^T + bb   (bf16)
        cvt(Wb, P.sA, (size_t)DH*DMODEL);
        gemm_bt<0,false><<<gH, blk, 0, stream>>>(P.xab, P.sA, DMODEL, nullptr, nullptr, 0,
                                                 nullptr, P.pBv, bb, nullptr, nullptr, Mp, DH);
        // chunked scan -> h_st (bf16)
        scan_chunks<<<dim3(DH/256, NCHUNK, nb), blk, 0, stream>>>(P.delta, P.pBv, Avec, P.cA, P.cB);
        scan_prefix<<<dim3(nb*DH/256), blk, 0, stream>>>(P.cA, P.cB, P.cH);
        scan_apply <<<dim3(DH/256, NCHUNK, nb), blk, 0, stream>>>(P.delta, P.pBv, Avec, P.cH, P.hstb);
        // oss = xa @ Wd^T + h_st @ Wc^T + (bd+bc)   (f32 + bf16 dual out, fused two-K GEMM)
        cvt(Wd, P.sA, (size_t)DMODEL*DMODEL);
        cvt(Wc, P.sB, (size_t)DMODEL*DH);
        gemm_bt<1,true><<<gD, blk, 0, stream>>>(P.xab, P.sA, DMODEL, P.hstb, P.sB, DH,
                                                P.oss, P.ossb, bd, bc, nullptr, Mp, DMODEL);
        // z = oss * silu(oss @ W2^T)
        cvt(W2, P.sA, (size_t)DMODEL*DMODEL);
        gemm_bt<2,false><<<gD, blk, 0, stream>>>(P.ossb, P.sA, DMODEL, nullptr, nullptr, 0,
                                                 nullptr, P.zb, nullptr, nullptr, P.oss, Mp, DMODEL);
        // out = oss + z @ Wlast^T
        cvt(Wlast, P.sA, (size_t)DMODEL*DMODEL);
        gemm_bt<3,false><<<gD, blk, 0, stream>>>(P.zb, P.sA, DMODEL, nullptr, nullptr, 0,
                                                 out_p, nullptr, nullptr, nullptr, P.oss, Mp, DMODEL);
    }
}

// Round 5
// 370.110 us; speedup vs baseline: 2.1665x; 1.0530x over previous
//
#include <hip/hip_runtime.h>
#include <cstdint>
#include <cstddef>

#define DMODEL 1024
#define DH 2048
#define BATCH 2
#define SEQ 4096
#define MROWS (BATCH*SEQ)    // 8192
#define CHUNK 64
#define NCHUNK (SEQ/CHUNK)   // 64

typedef unsigned short u16;
typedef __attribute__((ext_vector_type(8))) short bf16x8;
typedef __attribute__((ext_vector_type(4))) float f32x4;

__device__ __forceinline__ u16 f2bf(float f) {
    union { float f; unsigned u; } v; v.f = f;
    unsigned r = v.u + 0x7FFFu + ((v.u >> 16) & 1u);
    return (u16)(r >> 16);
}
__device__ __forceinline__ float bf2f(u16 h) {
    union { unsigned u; float f; } v; v.u = ((unsigned)h) << 16; return v.f;
}

// fast softplus: for x < -4, softplus(x) = log1p(e^x) ≈ e^x (rel err ≤ e^-4/2 ≈ 0.9%,
// typical x≈-8 → 1.7e-4). Exact branches are cold (bdelta = -8).
__device__ __forceinline__ float softplus_fast(float x) {
    if (x < -4.f) return __expf(x);
    return (x > 0.f) ? (x + log1pf(__expf(-x))) : log1pf(__expf(x));
}
__device__ __forceinline__ float silu_fast(float v) {
    return v * __fdividef(1.f, 1.f + __expf(-v));
}

// ---------------- f32 -> bf16, 4 elems/thread ----------------
__global__ void cvt_bf16(const float* __restrict__ src, u16* __restrict__ dst, int n4) {
    int i = blockIdx.x * blockDim.x + threadIdx.x;
    if (i >= n4) return;
    const float4 v = reinterpret_cast<const float4*>(src)[i];
    ushort4 o;
    o.x = f2bf(v.x); o.y = f2bf(v.y); o.z = f2bf(v.z); o.w = f2bf(v.w);
    reinterpret_cast<ushort4*>(dst)[i] = o;
}

// ---------------- GEMM: C[M,N] = A[M,K] @ B[N,K]^T  (bf16 in, f32 acc) ----------------
// 128x128 tile, BK=64, width-16 global_load_lds, XOR-swizzled LDS (both sides, rule 21),
// bijective XCD block swizzle (T1/m204; all grids have nwg%8==0).
// EP 0: Cb = bf16(acc + b1)
// EP 1: C  = acc + b1 + b2; Cb = bf16(C)       (fused Wd/Wc dual-out)
// EP 2: Cb = bf16(aux * silu(acc))             (gate)
// EP 3: C  = aux + acc                         (final residual, f32 out)
// EP 4: split N=2*DH: col<DH  -> Cb [row][col]     = bf16(softplus(acc+b1[col]))   (delta)
//                     col>=DH -> Cb2[row][col-DH]  = bf16(acc+b2[col-DH])          (pBv)
__device__ __forceinline__ void gload_lds16(const void* g, void* l) {
    __builtin_amdgcn_global_load_lds(
        (const __attribute__((address_space(1))) void*)g,
        (__attribute__((address_space(3))) void*)l,
        16, 0, 0);
}

template<int EP, bool TWOK>
__global__ __launch_bounds__(256) void gemm_bt(
    const u16* __restrict__ A1, const u16* __restrict__ B1, int K1,
    const u16* __restrict__ A2, const u16* __restrict__ B2, int K2,
    float* __restrict__ C, u16* __restrict__ Cb, u16* __restrict__ Cb2,
    const float* __restrict__ bias, const float* __restrict__ bias2,
    const float* __restrict__ aux,
    int M, int N)
{
    __shared__ u16 As[128*64];   // 16 KB
    __shared__ u16 Bs[128*64];   // 16 KB
    const int tid = threadIdx.x;

    // XCD-aware bijective block swizzle (nwg % 8 == 0 for all our grids)
    const int nwg = gridDim.x * gridDim.y;
    int wg = blockIdx.y * gridDim.x + blockIdx.x;
    wg = (wg & 7) * (nwg >> 3) + (wg >> 3);
    const int m0 = (wg / gridDim.x) * 128;
    const int n0 = (wg % gridDim.x) * 128;

    const int wave = tid >> 6, lane = tid & 63;
    const int wr = (wave >> 1) * 64;     // 2x2 wave grid, 64x64 per wave
    const int wc = (wave & 1) * 64;
    const int fr = lane & 15, fq = lane >> 4;

    f32x4 acc[4][4];
    #pragma unroll
    for (int m = 0; m < 4; m++)
        #pragma unroll
        for (int n = 0; n < 4; n++) acc[m][n] = f32x4{0.f, 0.f, 0.f, 0.f};

    const int nseg = TWOK ? 2 : 1;
    for (int seg = 0; seg < nseg; ++seg) {
        const u16* A = (TWOK && seg) ? A2 : A1;
        const u16* B = (TWOK && seg) ? B2 : B1;
        const int  K = (TWOK && seg) ? K2 : K1;
        for (int k0 = 0; k0 < K; k0 += 64) {
            #pragma unroll
            for (int i = 0; i < 4; ++i) {         // 1024 granules of 16B per matrix
                const int g = i*256 + tid;
                const int r = g >> 3;             // tile row
                const int ch = (g & 7) ^ (r & 7); // pre-swizzled source chunk
                gload_lds16(A + (size_t)(m0 + r)*K + (k0 + ch*8), (char*)As + (size_t)g*16);
                gload_lds16(B + (size_t)(n0 + r)*K + (k0 + ch*8), (char*)Bs + (size_t)g*16);
            }
            __syncthreads();
            #pragma unroll
            for (int kk = 0; kk < 2; ++kk) {
                bf16x8 af[4], bfr[4];
                #pragma unroll
                for (int m = 0; m < 4; m++) {
                    const int r = wr + m*16 + fr;
                    af[m] = *reinterpret_cast<const bf16x8*>(
                        (const char*)As + r*128 + (((kk*4 + fq) ^ (r & 7)) * 16));
                }
                #pragma unroll
                for (int n = 0; n < 4; n++) {
                    const int r = wc + n*16 + fr;
                    bfr[n] = *reinterpret_cast<const bf16x8*>(
                        (const char*)Bs + r*128 + (((kk*4 + fq) ^ (r & 7)) * 16));
                }
                #pragma unroll
                for (int m = 0; m < 4; m++)
                    #pragma unroll
                    for (int n = 0; n < 4; n++)
                        acc[m][n] = __builtin_amdgcn_mfma_f32_16x16x32_bf16(af[m], bfr[n], acc[m][n], 0, 0, 0);
            }
            __syncthreads();
        }
    }

    #pragma unroll
    for (int m = 0; m < 4; m++) {
        #pragma unroll
        for (int n = 0; n < 4; n++) {
            const int col = n0 + wc + n*16 + fr;
            float bv = 0.f;
            if constexpr (EP != 4) {
                if (bias)  bv += bias[col];
                if (bias2) bv += bias2[col];
            }
            #pragma unroll
            for (int j = 0; j < 4; j++) {
                const int row = m0 + wr + m*16 + fq*4 + j;   // C row = (lane>>4)*4+reg
                const size_t idx = (size_t)row * N + col;
                float v = acc[m][n][j] + bv;
                if constexpr (EP == 0) {
                    Cb[idx] = f2bf(v);
                } else if constexpr (EP == 1) {
                    C[idx] = v;
                    Cb[idx] = f2bf(v);
                } else if constexpr (EP == 2) {
                    Cb[idx] = f2bf(aux[idx] * silu_fast(v));
                } else if constexpr (EP == 3) {
                    C[idx] = aux[idx] + v;
                } else {   // EP 4: merged delta | pBv (block-uniform split at col==DH)
                    if (col < DH) {
                        Cb [(size_t)row*DH + col]        = f2bf(softplus_fast(v + bias[col]));
                    } else {
                        Cb2[(size_t)row*DH + (col - DH)] = f2bf(v + bias2[col - DH]);
                    }
                }
            }
        }
    }
}

// ---------------- depthwise conv3 (pad 1, per seq of 4096) + silu, bf16x8 ----------------
__global__ void conv_silu8(const u16* __restrict__ x1, const float* __restrict__ cw,
                           const float* __restrict__ cb, u16* __restrict__ xab) {
    int t = blockIdx.x * blockDim.x + threadIdx.x;   // over Mp*DMODEL/8
    int c8  = t & (DMODEL/8 - 1);
    int row = t >> 7;
    int l = row & (SEQ - 1);
    const int c0 = c8 * 8;
    const size_t i0 = (size_t)row * DMODEL + c0;
    bf16x8 v0 = *reinterpret_cast<const bf16x8*>(x1 + i0);
    bf16x8 vm = {}; if (l > 0)       vm = *reinterpret_cast<const bf16x8*>(x1 + i0 - DMODEL);
    bf16x8 vp = {}; if (l < SEQ - 1) vp = *reinterpret_cast<const bf16x8*>(x1 + i0 + DMODEL);
    if (l == 0)       vm = bf16x8{};
    if (l == SEQ - 1) vp = bf16x8{};
    bf16x8 o;
    #pragma unroll
    for (int j = 0; j < 8; ++j) {
        const int c = c0 + j;
        float v = cw[c*3+0]*bf2f((u16)vm[j]) + cw[c*3+1]*bf2f((u16)v0[j])
                + cw[c*3+2]*bf2f((u16)vp[j]) + cb[c];
        o[j] = (short)f2bf(silu_fast(v));
    }
    *reinterpret_cast<bf16x8*>(xab + i0) = o;
}

// ---------------- SSM chunked scan (batch in grid.z) ----------------
// delta (bf16, softplus applied) and pBv = pre_B + bb (bf16) precomputed by GEMM epilogue.
__global__ void scan_chunks(const u16* __restrict__ delta, const u16* __restrict__ pBv,
                            const float* __restrict__ Avec,
                            float* __restrict__ cA, float* __restrict__ cB) {
    const int c = blockIdx.x * blockDim.x + threadIdx.x;
    const int q = blockIdx.y;
    const int b = blockIdx.z;
    const float Ac = Avec[c];
    float hA = 1.f, hB = 0.f;
    size_t base = ((size_t)b*SEQ + q*CHUNK)*DH + c;
    for (int j = 0; j < CHUNK; ++j) {
        float d = bf2f(delta[base]);
        float Abar = __expf(d * Ac);
        hA *= Abar;
        hB = Abar*hB + d * bf2f(pBv[base]);
        base += DH;
    }
    size_t o = ((size_t)b*NCHUNK + q)*DH + c;
    cA[o] = hA; cB[o] = hB;
}

__global__ void scan_prefix(const float* __restrict__ cA, const float* __restrict__ cB,
                            float* __restrict__ cH) {
    const int t = blockIdx.x * blockDim.x + threadIdx.x;   // nb*DH
    const int b = t >> 11;          // /DH
    const int c = t & (DH - 1);
    float h = 0.f;
    size_t o = ((size_t)b*NCHUNK)*DH + c;
    float a = cA[o], bb = cB[o];
    for (int q = 0; q < NCHUNK; ++q) {
        const size_t on = o + DH;
        float a2 = 0.f, b2 = 0.f;
        if (q + 1 < NCHUNK) { a2 = cA[on]; b2 = cB[on]; }   // prefetch next
        cH[o] = h;                   // state BEFORE chunk q
        h = a*h + bb;
        a = a2; bb = b2; o = on;
    }
}

__global__ void scan_apply(const u16* __restrict__ delta, const u16* __restrict__ pBv,
                           const float* __restrict__ Avec, const float* __restrict__ cH,
                           u16* __restrict__ hstb) {
    const int c = blockIdx.x * blockDim.x + threadIdx.x;
    const int q = blockIdx.y;
    const int b = blockIdx.z;
    const float Ac = Avec[c];
    float h = cH[((size_t)b*NCHUNK + q)*DH + c];
    size_t base = ((size_t)b*SEQ + q*CHUNK)*DH + c;
    for (int j = 0; j < CHUNK; ++j) {
        float d = bf2f(delta[base]);
        float Abar = __expf(d * Ac);
        h = Abar*h + d * bf2f(pBv[base]);
        hstb[base] = f2bf(h);
        base += DH;
    }
}

// ---------------- host ----------------
extern "C" void kernel_launch(void* const* d_in, const int* in_sizes, int n_in,
                              void* d_out, int out_size, void* d_ws, size_t ws_size,
                              hipStream_t stream) {
    const float* x      = (const float*)d_in[0];
    const float* W1     = (const float*)d_in[1];
    const float* conv_w = (const float*)d_in[2];
    const float* conv_b = (const float*)d_in[3];
    const float* Avec   = (const float*)d_in[4];
    const float* Wb     = (const float*)d_in[5];
    const float* bb     = (const float*)d_in[6];
    const float* Wc     = (const float*)d_in[7];
    const float* bc     = (const float*)d_in[8];
    const float* Wd     = (const float*)d_in[9];
    const float* bd     = (const float*)d_in[10];
    const float* Wdelta = (const float*)d_in[11];
    const float* bdelta = (const float*)d_in[12];
    const float* W2     = (const float*)d_in[13];
    const float* Wlast  = (const float*)d_in[14];
    float* out = (float*)d_out;
    (void)in_sizes; (void)n_in; (void)out_size;

    // ---- layout (aliased by lifetime); prefer full-batch (1 pass), else 2 passes ----
    struct Ptrs {
        u16 *sW;                  // 8 MB weight slot (Wdelta|Wb merged, or Wd|Wc, or single)
        float *cA, *cB, *cH;
        u16 *xb, *x1b, *xab, *delta, *pBv, *ossb, *hstb, *zb;
        float *oss;
        size_t total;
    };
    auto layout = [&](int passes) -> Ptrs {
        Ptrs P{};
        const size_t Mp = MROWS / passes;
        const int nb = BATCH / passes;
        size_t off = 0;
        auto al = [&](size_t bytes) -> char* {
            char* p = (char*)d_ws + off; off += (bytes + 255) & ~(size_t)255; return p;
        };
        P.sW  = (u16*)al((size_t)2*DH*DMODEL*2);      // 8 MB
        P.cA  = (float*)al((size_t)nb*NCHUNK*DH*4);
        P.cB  = (float*)al((size_t)nb*NCHUNK*DH*4);
        P.cH  = (float*)al((size_t)nb*NCHUNK*DH*4);
        char* RA = al(Mp*DMODEL*2);                   // xb -> ossb
        char* RB = al(Mp*DMODEL*2);                   // x1b -> zb
        char* RC = al(Mp*DMODEL*2);                   // xab
        char* RD = al(Mp*DH*2);                       // delta -> oss (f32 Mp*DMODEL*4, same bytes)
        char* RE = al(Mp*DH*2);                       // pBv
        char* RF = al(Mp*DH*2);                       // hstb
        P.xb    = (u16*)RA; P.ossb = (u16*)RA;
        P.x1b   = (u16*)RB; P.zb   = (u16*)RB;
        P.xab   = (u16*)RC;
        P.delta = (u16*)RD; P.oss  = (float*)RD;
        P.pBv   = (u16*)RE;
        P.hstb  = (u16*)RF;
        P.total = off;
        return P;
    };

    int passes = (ws_size >= layout(1).total) ? 1 : 2;
    Ptrs P = layout(passes);
    if (ws_size < P.total) return;   // clean diagnostic fail instead of fault
    const int Mp = MROWS / passes;
    const int nb = BATCH / passes;

    const dim3 blk(256);
    auto cvt = [&](const float* s, u16* d, size_t n) {
        int n4 = (int)(n / 4);
        cvt_bf16<<<dim3((n4 + 255)/256), blk, 0, stream>>>(s, d, n4);
    };
    const dim3 gD (DMODEL/128,   Mp/128);   // 512 blocks (1-pass)
    const dim3 gDB(2*DH/128,     Mp/128);   // 2048 blocks (merged delta|pBv)
    u16* sW2 = P.sW + (size_t)DH*DMODEL;    // second half of weight slot

    for (int p = 0; p < passes; ++p) {
        const float* x_p  = x  + (size_t)p*Mp*DMODEL;
        float*      out_p = out + (size_t)p*Mp*DMODEL;

        cvt(x_p, P.xb, (size_t)Mp*DMODEL);
        // x1 = x @ W1^T
        cvt(W1, P.sW, (size_t)DMODEL*DMODEL);
        gemm_bt<0,false><<<gD, blk, 0, stream>>>(P.xb, P.sW, DMODEL, nullptr, nullptr, 0,
                                                 nullptr, P.x1b, nullptr, nullptr, nullptr, nullptr, Mp, DMODEL);
        // xa = silu(conv3(x1))
        conv_silu8<<<dim3(Mp*DMODEL/8/256), blk, 0, stream>>>(P.x1b, conv_w, conv_b, P.xab);
        // merged: delta = softplus(xa@Wdelta^T + bdelta), pBv = xa@Wb^T + bb  (one N=4096 GEMM)
        cvt(Wdelta, P.sW, (size_t)DH*DMODEL);
        cvt(Wb,     sW2,  (size_t)DH*DMODEL);
        gemm_bt<4,false><<<gDB, blk, 0, stream>>>(P.xab, P.sW, DMODEL, nullptr, nullptr, 0,
                                                  nullptr, P.delta, P.pBv, bdelta, bb, nullptr, Mp, 2*DH);
        // chunked scan -> h_st (bf16)
        scan_chunks<<<dim3(DH/256, NCHUNK, nb), blk, 0, stream>>>(P.delta, P.pBv, Avec, P.cA, P.cB);
        scan_prefix<<<dim3(nb*DH/256), blk, 0, stream>>>(P.cA, P.cB, P.cH);
        scan_apply <<<dim3(DH/256, NCHUNK, nb), blk, 0, stream>>>(P.delta, P.pBv, Avec, P.cH, P.hstb);
        // oss = xa @ Wd^T + h_st @ Wc^T + (bd+bc)   (f32 + bf16 dual out, fused two-K GEMM)
        cvt(Wd, P.sW, (size_t)DMODEL*DMODEL);
        cvt(Wc, sW2,  (size_t)DMODEL*DH);
        gemm_bt<1,true><<<gD, blk, 0, stream>>>(P.xab, P.sW, DMODEL, P.hstb, sW2, DH,
                                                P.oss, P.ossb, nullptr, bd, bc, nullptr, Mp, DMODEL);
        // z = oss * silu(oss @ W2^T)
        cvt(W2, P.sW, (size_t)DMODEL*DMODEL);
        gemm_bt<2,false><<<gD, blk, 0, stream>>>(P.ossb, P.sW, DMODEL, nullptr, nullptr, 0,
                                                 nullptr, P.zb, nullptr, nullptr, nullptr, P.oss, Mp, DMODEL);
        // out = oss + z @ Wlast^T
        cvt(Wlast, P.sW, (size_t)DMODEL*DMODEL);
        gemm_bt<3,false><<<gD, blk, 0, stream>>>(P.zb, P.sW, DMODEL, nullptr, nullptr, 0,
                                                 out_p, nullptr, nullptr, nullptr, nullptr, P.oss, Mp, DMODEL);
    }
}

// Round 6
// 352.713 us; speedup vs baseline: 2.2734x; 1.0493x over previous
//
#include <hip/hip_runtime.h>
#include <cstdint>
#include <cstddef>

#define DMODEL 1024
#define DH 2048
#define BATCH 2
#define SEQ 4096
#define MROWS (BATCH*SEQ)    // 8192
#define CHUNK 64
#define NCHUNK (SEQ/CHUNK)   // 64

typedef unsigned short u16;
typedef __attribute__((ext_vector_type(8))) short bf16x8;
typedef __attribute__((ext_vector_type(4))) float f32x4;

__device__ __forceinline__ u16 f2bf(float f) {
    union { float f; unsigned u; } v; v.f = f;
    unsigned r = v.u + 0x7FFFu + ((v.u >> 16) & 1u);
    return (u16)(r >> 16);
}
__device__ __forceinline__ float bf2f(u16 h) {
    union { unsigned u; float f; } v; v.u = ((unsigned)h) << 16; return v.f;
}

// fast softplus: for x < -4, softplus(x) = log1p(e^x) ≈ e^x (rel err ≤ e^-4/2 ≈ 0.9%,
// typical x≈-8 → 1.7e-4). Exact branches are cold (bdelta = -8).
__device__ __forceinline__ float softplus_fast(float x) {
    if (x < -4.f) return __expf(x);
    return (x > 0.f) ? (x + log1pf(__expf(-x))) : log1pf(__expf(x));
}
__device__ __forceinline__ float silu_fast(float v) {
    return v * __fdividef(1.f, 1.f + __expf(-v));
}

// ---------------- f32 -> bf16, 4 elems/thread ----------------
__global__ void cvt_bf16(const float* __restrict__ src, u16* __restrict__ dst, int n4) {
    int i = blockIdx.x * blockDim.x + threadIdx.x;
    if (i >= n4) return;
    const float4 v = reinterpret_cast<const float4*>(src)[i];
    ushort4 o;
    o.x = f2bf(v.x); o.y = f2bf(v.y); o.z = f2bf(v.z); o.w = f2bf(v.w);
    reinterpret_cast<ushort4*>(dst)[i] = o;
}

// ---------------- GEMM: C[M,N] = A[M,K] @ B[N,K]^T  (bf16 in, f32 acc) ----------------
// 128x128 tile, BK=64, width-16 global_load_lds, XOR-swizzled LDS (both sides, rule 21),
// bijective XCD block swizzle, and a 2-phase double-buffered pipeline (m248 recipe):
// per iter {STAGE(next -> other buf); compute(cur); vmcnt(0); s_barrier} — one barrier
// per K-step, stage latency hidden under the MFMAs.
// EP 0: Cb = bf16(acc + b1)
// EP 1: C  = acc + b1 + b2; Cb = bf16(C)       (fused Wd/Wc dual-out)
// EP 2: Cb = bf16(aux * silu(acc))             (gate)
// EP 3: C  = aux + acc                         (final residual, f32 out)
// EP 4: split N=2*DH: col<DH  -> Cb [row][col]     = bf16(softplus(acc+b1[col]))   (delta)
//                     col>=DH -> Cb2[row][col-DH]  = bf16(acc+b2[col-DH])          (pBv)
__device__ __forceinline__ void gload_lds16(const void* g, void* l) {
    __builtin_amdgcn_global_load_lds(
        (const __attribute__((address_space(1))) void*)g,
        (__attribute__((address_space(3))) void*)l,
        16, 0, 0);
}

template<int EP, bool TWOK>
__global__ __launch_bounds__(256) void gemm_bt(
    const u16* __restrict__ A1, const u16* __restrict__ B1, int K1,
    const u16* __restrict__ A2, const u16* __restrict__ B2, int K2,
    float* __restrict__ C, u16* __restrict__ Cb, u16* __restrict__ Cb2,
    const float* __restrict__ bias, const float* __restrict__ bias2,
    const float* __restrict__ aux,
    int M, int N)
{
    __shared__ u16 As[2][128*64];   // 2 x 16 KB
    __shared__ u16 Bs[2][128*64];   // 2 x 16 KB  (64 KB total)
    const int tid = threadIdx.x;

    // XCD-aware bijective block swizzle (nwg % 8 == 0 for all our grids)
    const int nwg = gridDim.x * gridDim.y;
    int wg = blockIdx.y * gridDim.x + blockIdx.x;
    wg = (wg & 7) * (nwg >> 3) + (wg >> 3);
    const int m0 = (wg / gridDim.x) * 128;
    const int n0 = (wg % gridDim.x) * 128;

    const int wave = tid >> 6, lane = tid & 63;
    const int wr = (wave >> 1) * 64;     // 2x2 wave grid, 64x64 per wave
    const int wc = (wave & 1) * 64;
    const int fr = lane & 15, fq = lane >> 4;

    f32x4 acc[4][4];
    #pragma unroll
    for (int m = 0; m < 4; m++)
        #pragma unroll
        for (int n = 0; n < 4; n++) acc[m][n] = f32x4{0.f, 0.f, 0.f, 0.f};

    const int nt1 = K1 >> 6;
    const int nt  = TWOK ? nt1 + (K2 >> 6) : nt1;

    auto stage = [&](int t, int buf) {
        const u16* A = A1; const u16* B = B1; int K = K1; int k0 = t << 6;
        if (TWOK && t >= nt1) { A = A2; B = B2; K = K2; k0 = (t - nt1) << 6; }
        #pragma unroll
        for (int i = 0; i < 4; ++i) {            // 1024 granules of 16B per matrix
            const int g = i*256 + tid;
            const int r = g >> 3;                // tile row
            const int ch = (g & 7) ^ (r & 7);    // pre-swizzled source chunk
            gload_lds16(A + (size_t)(m0 + r)*K + (k0 + ch*8), (char*)As[buf] + (size_t)g*16);
            gload_lds16(B + (size_t)(n0 + r)*K + (k0 + ch*8), (char*)Bs[buf] + (size_t)g*16);
        }
    };

    auto compute = [&](int buf) {
        #pragma unroll
        for (int kk = 0; kk < 2; ++kk) {
            bf16x8 af[4], bfr[4];
            #pragma unroll
            for (int m = 0; m < 4; m++) {
                const int r = wr + m*16 + fr;
                af[m] = *reinterpret_cast<const bf16x8*>(
                    (const char*)As[buf] + r*128 + (((kk*4 + fq) ^ (r & 7)) * 16));
            }
            #pragma unroll
            for (int n = 0; n < 4; n++) {
                const int r = wc + n*16 + fr;
                bfr[n] = *reinterpret_cast<const bf16x8*>(
                    (const char*)Bs[buf] + r*128 + (((kk*4 + fq) ^ (r & 7)) * 16));
            }
            #pragma unroll
            for (int m = 0; m < 4; m++)
                #pragma unroll
                for (int n = 0; n < 4; n++)
                    acc[m][n] = __builtin_amdgcn_mfma_f32_16x16x32_bf16(af[m], bfr[n], acc[m][n], 0, 0, 0);
        }
    };

    // prologue: fill buf0
    stage(0, 0);
    asm volatile("s_waitcnt vmcnt(0)" ::: "memory");
    __builtin_amdgcn_s_barrier();
    __builtin_amdgcn_sched_barrier(0);

    int cur = 0;
    for (int t = 0; t < nt; ++t) {
        if (t + 1 < nt) stage(t + 1, cur ^ 1);   // issue next-tile loads first
        compute(cur);                            // MFMAs hide the load latency
        asm volatile("s_waitcnt vmcnt(0)" ::: "memory");   // next tile landed
        __builtin_amdgcn_s_barrier();            // all waves done with cur + loads landed
        __builtin_amdgcn_sched_barrier(0);
        cur ^= 1;
    }

    #pragma unroll
    for (int m = 0; m < 4; m++) {
        #pragma unroll
        for (int n = 0; n < 4; n++) {
            const int col = n0 + wc + n*16 + fr;
            float bv = 0.f;
            if constexpr (EP != 4) {
                if (bias)  bv += bias[col];
                if (bias2) bv += bias2[col];
            }
            #pragma unroll
            for (int j = 0; j < 4; j++) {
                const int row = m0 + wr + m*16 + fq*4 + j;   // C row = (lane>>4)*4+reg
                const size_t idx = (size_t)row * N + col;
                float v = acc[m][n][j] + bv;
                if constexpr (EP == 0) {
                    Cb[idx] = f2bf(v);
                } else if constexpr (EP == 1) {
                    C[idx] = v;
                    Cb[idx] = f2bf(v);
                } else if constexpr (EP == 2) {
                    Cb[idx] = f2bf(aux[idx] * silu_fast(v));
                } else if constexpr (EP == 3) {
                    C[idx] = aux[idx] + v;
                } else {   // EP 4: merged delta | pBv (block-uniform split at col==DH)
                    if (col < DH) {
                        Cb [(size_t)row*DH + col]        = f2bf(softplus_fast(v + bias[col]));
                    } else {
                        Cb2[(size_t)row*DH + (col - DH)] = f2bf(v + bias2[col - DH]);
                    }
                }
            }
        }
    }
}

// ---------------- depthwise conv3 (pad 1, per seq of 4096) + silu, bf16x8 ----------------
__global__ void conv_silu8(const u16* __restrict__ x1, const float* __restrict__ cw,
                           const float* __restrict__ cb, u16* __restrict__ xab) {
    int t = blockIdx.x * blockDim.x + threadIdx.x;   // over Mp*DMODEL/8
    int c8  = t & (DMODEL/8 - 1);
    int row = t >> 7;
    int l = row & (SEQ - 1);
    const int c0 = c8 * 8;
    const size_t i0 = (size_t)row * DMODEL + c0;
    bf16x8 v0 = *reinterpret_cast<const bf16x8*>(x1 + i0);
    bf16x8 vm = {}; if (l > 0)       vm = *reinterpret_cast<const bf16x8*>(x1 + i0 - DMODEL);
    bf16x8 vp = {}; if (l < SEQ - 1) vp = *reinterpret_cast<const bf16x8*>(x1 + i0 + DMODEL);
    if (l == 0)       vm = bf16x8{};
    if (l == SEQ - 1) vp = bf16x8{};
    bf16x8 o;
    #pragma unroll
    for (int j = 0; j < 8; ++j) {
        const int c = c0 + j;
        float v = cw[c*3+0]*bf2f((u16)vm[j]) + cw[c*3+1]*bf2f((u16)v0[j])
                + cw[c*3+2]*bf2f((u16)vp[j]) + cb[c];
        o[j] = (short)f2bf(silu_fast(v));
    }
    *reinterpret_cast<bf16x8*>(xab + i0) = o;
}

// ---------------- SSM chunked scan (batch in grid.z) ----------------
__global__ void scan_chunks(const u16* __restrict__ delta, const u16* __restrict__ pBv,
                            const float* __restrict__ Avec,
                            float* __restrict__ cA, float* __restrict__ cB) {
    const int c = blockIdx.x * blockDim.x + threadIdx.x;
    const int q = blockIdx.y;
    const int b = blockIdx.z;
    const float Ac = Avec[c];
    float hA = 1.f, hB = 0.f;
    size_t base = ((size_t)b*SEQ + q*CHUNK)*DH + c;
    for (int j = 0; j < CHUNK; ++j) {
        float d = bf2f(delta[base]);
        float Abar = __expf(d * Ac);
        hA *= Abar;
        hB = Abar*hB + d * bf2f(pBv[base]);
        base += DH;
    }
    size_t o = ((size_t)b*NCHUNK + q)*DH + c;
    cA[o] = hA; cB[o] = hB;
}

__global__ void scan_prefix(const float* __restrict__ cA, const float* __restrict__ cB,
                            float* __restrict__ cH) {
    const int t = blockIdx.x * blockDim.x + threadIdx.x;   // nb*DH
    const int b = t >> 11;          // /DH
    const int c = t & (DH - 1);
    float h = 0.f;
    size_t o = ((size_t)b*NCHUNK)*DH + c;
    float a = cA[o], bb = cB[o];
    for (int q = 0; q < NCHUNK; ++q) {
        const size_t on = o + DH;
        float a2 = 0.f, b2 = 0.f;
        if (q + 1 < NCHUNK) { a2 = cA[on]; b2 = cB[on]; }   // prefetch next
        cH[o] = h;                   // state BEFORE chunk q
        h = a*h + bb;
        a = a2; bb = b2; o = on;
    }
}

__global__ void scan_apply(const u16* __restrict__ delta, const u16* __restrict__ pBv,
                           const float* __restrict__ Avec, const float* __restrict__ cH,
                           u16* __restrict__ hstb) {
    const int c = blockIdx.x * blockDim.x + threadIdx.x;
    const int q = blockIdx.y;
    const int b = blockIdx.z;
    const float Ac = Avec[c];
    float h = cH[((size_t)b*NCHUNK + q)*DH + c];
    size_t base = ((size_t)b*SEQ + q*CHUNK)*DH + c;
    for (int j = 0; j < CHUNK; ++j) {
        float d = bf2f(delta[base]);
        float Abar = __expf(d * Ac);
        h = Abar*h + d * bf2f(pBv[base]);
        hstb[base] = f2bf(h);
        base += DH;
    }
}

// ---------------- host ----------------
extern "C" void kernel_launch(void* const* d_in, const int* in_sizes, int n_in,
                              void* d_out, int out_size, void* d_ws, size_t ws_size,
                              hipStream_t stream) {
    const float* x      = (const float*)d_in[0];
    const float* W1     = (const float*)d_in[1];
    const float* conv_w = (const float*)d_in[2];
    const float* conv_b = (const float*)d_in[3];
    const float* Avec   = (const float*)d_in[4];
    const float* Wb     = (const float*)d_in[5];
    const float* bb     = (const float*)d_in[6];
    const float* Wc     = (const float*)d_in[7];
    const float* bc     = (const float*)d_in[8];
    const float* Wd     = (const float*)d_in[9];
    const float* bd     = (const float*)d_in[10];
    const float* Wdelta = (const float*)d_in[11];
    const float* bdelta = (const float*)d_in[12];
    const float* W2     = (const float*)d_in[13];
    const float* Wlast  = (const float*)d_in[14];
    float* out = (float*)d_out;
    (void)in_sizes; (void)n_in; (void)out_size;

    // ---- layout (aliased by lifetime); prefer full-batch (1 pass), else 2 passes ----
    struct Ptrs {
        u16 *sW;                  // 8 MB weight slot (Wdelta|Wb merged, or Wd|Wc, or single)
        float *cA, *cB, *cH;
        u16 *xb, *x1b, *xab, *delta, *pBv, *ossb, *hstb, *zb;
        float *oss;
        size_t total;
    };
    auto layout = [&](int passes) -> Ptrs {
        Ptrs P{};
        const size_t Mp = MROWS / passes;
        const int nb = BATCH / passes;
        size_t off = 0;
        auto al = [&](size_t bytes) -> char* {
            char* p = (char*)d_ws + off; off += (bytes + 255) & ~(size_t)255; return p;
        };
        P.sW  = (u16*)al((size_t)2*DH*DMODEL*2);      // 8 MB
        P.cA  = (float*)al((size_t)nb*NCHUNK*DH*4);
        P.cB  = (float*)al((size_t)nb*NCHUNK*DH*4);
        P.cH  = (float*)al((size_t)nb*NCHUNK*DH*4);
        char* RA = al(Mp*DMODEL*2);                   // xb -> ossb
        char* RB = al(Mp*DMODEL*2);                   // x1b -> zb
        char* RC = al(Mp*DMODEL*2);                   // xab
        char* RD = al(Mp*DH*2);                       // delta -> oss (f32 Mp*DMODEL*4, same bytes)
        char* RE = al(Mp*DH*2);                       // pBv
        char* RF = al(Mp*DH*2);                       // hstb
        P.xb    = (u16*)RA; P.ossb = (u16*)RA;
        P.x1b   = (u16*)RB; P.zb   = (u16*)RB;
        P.xab   = (u16*)RC;
        P.delta = (u16*)RD; P.oss  = (float*)RD;
        P.pBv   = (u16*)RE;
        P.hstb  = (u16*)RF;
        P.total = off;
        return P;
    };

    int passes = (ws_size >= layout(1).total) ? 1 : 2;
    Ptrs P = layout(passes);
    if (ws_size < P.total) return;   // clean diagnostic fail instead of fault
    const int Mp = MROWS / passes;
    const int nb = BATCH / passes;

    const dim3 blk(256);
    auto cvt = [&](const float* s, u16* d, size_t n) {
        int n4 = (int)(n / 4);
        cvt_bf16<<<dim3((n4 + 255)/256), blk, 0, stream>>>(s, d, n4);
    };
    const dim3 gD (DMODEL/128,   Mp/128);   // 512 blocks (1-pass)
    const dim3 gDB(2*DH/128,     Mp/128);   // 2048 blocks (merged delta|pBv)
    u16* sW2 = P.sW + (size_t)DH*DMODEL;    // second half of weight slot

    for (int p = 0; p < passes; ++p) {
        const float* x_p  = x  + (size_t)p*Mp*DMODEL;
        float*      out_p = out + (size_t)p*Mp*DMODEL;

        cvt(x_p, P.xb, (size_t)Mp*DMODEL);
        // x1 = x @ W1^T
        cvt(W1, P.sW, (size_t)DMODEL*DMODEL);
        gemm_bt<0,false><<<gD, blk, 0, stream>>>(P.xb, P.sW, DMODEL, nullptr, nullptr, 0,
                                                 nullptr, P.x1b, nullptr, nullptr, nullptr, nullptr, Mp, DMODEL);
        // xa = silu(conv3(x1))
        conv_silu8<<<dim3(Mp*DMODEL/8/256), blk, 0, stream>>>(P.x1b, conv_w, conv_b, P.xab);
        // merged: delta = softplus(xa@Wdelta^T + bdelta), pBv = xa@Wb^T + bb  (one N=4096 GEMM)
        cvt(Wdelta, P.sW, (size_t)DH*DMODEL);
        cvt(Wb,     sW2,  (size_t)DH*DMODEL);
        gemm_bt<4,false><<<gDB, blk, 0, stream>>>(P.xab, P.sW, DMODEL, nullptr, nullptr, 0,
                                                  nullptr, P.delta, P.pBv, bdelta, bb, nullptr, Mp, 2*DH);
        // chunked scan -> h_st (bf16)
        scan_chunks<<<dim3(DH/256, NCHUNK, nb), blk, 0, stream>>>(P.delta, P.pBv, Avec, P.cA, P.cB);
        scan_prefix<<<dim3(nb*DH/256), blk, 0, stream>>>(P.cA, P.cB, P.cH);
        scan_apply <<<dim3(DH/256, NCHUNK, nb), blk, 0, stream>>>(P.delta, P.pBv, Avec, P.cH, P.hstb);
        // oss = xa @ Wd^T + h_st @ Wc^T + (bd+bc)   (f32 + bf16 dual out, fused two-K GEMM)
        cvt(Wd, P.sW, (size_t)DMODEL*DMODEL);
        cvt(Wc, sW2,  (size_t)DMODEL*DH);
        gemm_bt<1,true><<<gD, blk, 0, stream>>>(P.xab, P.sW, DMODEL, P.hstb, sW2, DH,
                                                P.oss, P.ossb, nullptr, bd, bc, nullptr, Mp, DMODEL);
        // z = oss * silu(oss @ W2^T)
        cvt(W2, P.sW, (size_t)DMODEL*DMODEL);
        gemm_bt<2,false><<<gD, blk, 0, stream>>>(P.ossb, P.sW, DMODEL, nullptr, nullptr, 0,
                                                 nullptr, P.zb, nullptr, nullptr, nullptr, P.oss, Mp, DMODEL);
        // out = oss + z @ Wlast^T
        cvt(Wlast, P.sW, (size_t)DMODEL*DMODEL);
        gemm_bt<3,false><<<gD, blk, 0, stream>>>(P.zb, P.sW, DMODEL, nullptr, nullptr, 0,
                                                 out_p, nullptr, nullptr, nullptr, nullptr, P.oss, Mp, DMODEL);
    }
}